// Round 6
// baseline (295.781 us; speedup 1.0000x reference)
//
#include <hip/hip_runtime.h>
#include <hip/hip_bf16.h>

typedef float f32x4 __attribute__((ext_vector_type(4)));

#define NB 32      // batch
#define NT 2000    // time
#define NW 512     // width
#define NG 20      // groups (T / NUM_STEPS)
#define NS 100     // NUM_STEPS
#define NH 1024    // hidden
#define NO 10      // outputs
#define BETA 0.95f
#define THRESH 1.0f

// ---------------- Kernel 1: fused 1x1 conv + 100-step leaky scan ----------------
// ROUND-3 VERSION, proven ~78us (marginal-measured round 5) = HBM roofline.
__global__ __launch_bounds__(256) void k1_conv_scan(
    const f32x4* __restrict__ x,    // [B][T][W] of float4 (C=4 innermost)
    const float* __restrict__ cw,   // [4]
    const float* __restrict__ cb,   // [1]
    float* __restrict__ spk1)       // [B][G][W]
{
    int bid = blockIdx.x;           // 0..1279
    int half = bid & 1;             // which half of the 512-wide row
    int bg = bid >> 1;              // 0..639
    int g = bg % NG;
    int b = bg / NG;
    int tid = threadIdx.x;          // 0..255

    const f32x4* __restrict__ base =
        x + ((size_t)(b * NT + g * NS) * NW + half * 256);

    float w0 = cw[0], w1 = cw[1], w2 = cw[2], w3 = cw[3];
    float bias = cb[0];

    f32x4 A[10], B[10];
    float mem = 0.0f;

#define LOAD10(dst, S0)                                                        \
    {                                                                          \
        _Pragma("unroll")                                                      \
        for (int j = 0; j < 10; ++j)                                           \
            dst[j] = __builtin_nontemporal_load(base + (tid + ((S0) + j) * NW)); \
    }
#define STEP10(src)                                                            \
    {                                                                          \
        _Pragma("unroll")                                                      \
        for (int j = 0; j < 10; ++j) {                                         \
            f32x4 v = src[j];                                                  \
            float f = fmaf(v[0], w0, fmaf(v[1], w1,                            \
                      fmaf(v[2], w2, fmaf(v[3], w3, bias))));                  \
            float base_m = fmaf(BETA, mem, f);                                 \
            mem = (mem > THRESH) ? 0.0f : base_m;                              \
        }                                                                      \
    }

    LOAD10(A, 0)
    LOAD10(B, 10) STEP10(A)
    LOAD10(A, 20) STEP10(B)
    LOAD10(B, 30) STEP10(A)
    LOAD10(A, 40) STEP10(B)
    LOAD10(B, 50) STEP10(A)
    LOAD10(A, 60) STEP10(B)
    LOAD10(B, 70) STEP10(A)
    LOAD10(A, 80) STEP10(B)
    LOAD10(B, 90) STEP10(A)
    STEP10(B)
#undef LOAD10
#undef STEP10

    spk1[(b * NG + g) * NW + half * 256 + tid] = (mem > THRESH) ? 1.0f : 0.0f;
}

// ---------------- Transpose hidden_w (1024x512 -> 512x1024) ----------------
__global__ __launch_bounds__(256) void k_transpose(
    const float* __restrict__ wsrc,  // [H][W]
    float* __restrict__ wT)          // [W][H]
{
    __shared__ float tile[32][33];
    int bk = blockIdx.x;             // 16 tiles over W
    int bh = blockIdx.y;             // 32 tiles over H
    int tx = threadIdx.x;            // 0..31
    int ty = threadIdx.y;            // 0..7
    #pragma unroll
    for (int j = 0; j < 4; ++j)
        tile[ty + j * 8][tx] = wsrc[(bh * 32 + ty + j * 8) * NW + bk * 32 + tx];
    __syncthreads();
    #pragma unroll
    for (int j = 0; j < 4; ++j)
        wT[(bk * 32 + ty + j * 8) * NH + bh * 32 + tx] = tile[tx][ty + j * 8];
}

// ---------------- Kernel 2: hidden GEMM (4-way k-split) + 20-step scan ----------
// THIS ROUND: launched 5x (idempotent) to measure t(k2)+gap via
// (dur - 134.5)/4. Remove duplicates next round.
__global__ __launch_bounds__(256) void k2_hidden_scan(
    const float* __restrict__ spk1,  // [B][G][W]
    const float* __restrict__ wT,    // [W][H]
    const float* __restrict__ hb,    // [H]
    float* __restrict__ spk2)        // [B][H]
{
    int bid = blockIdx.x;            // 0..511
    int b = bid >> 4;                // 0..31
    int hgrp = bid & 15;             // 0..15
    int t = threadIdx.x;
    int lane = t & 63;
    int c = t >> 6;                  // k-chunk 0..3
    int h = hgrp * 64 + lane;

    const float* __restrict__ sp = spk1 + (size_t)b * NG * NW;  // uniform

    float acc[NG];
    #pragma unroll
    for (int g = 0; g < NG; ++g) acc[g] = 0.0f;

    int k0 = c * 128;
    for (int kk = k0; kk < k0 + 128; kk += 4) {
        float a0 = wT[(kk + 0) * NH + h];
        float a1 = wT[(kk + 1) * NH + h];
        float a2 = wT[(kk + 2) * NH + h];
        float a3 = wT[(kk + 3) * NH + h];
        #pragma unroll
        for (int g = 0; g < NG; ++g) {
            float4 u = *(const float4*)(sp + g * NW + kk);  // uniform -> s_load
            acc[g] += u.x * a0 + u.y * a1 + u.z * a2 + u.w * a3;
        }
    }

    __shared__ float red[4][NG][64];
    #pragma unroll
    for (int g = 0; g < NG; ++g) red[c][g][lane] = acc[g];
    __syncthreads();

    if (t < 64) {
        float hbias = hb[h];
        float mem = 0.0f;
        #pragma unroll
        for (int g = 0; g < NG; ++g) {
            float xin = red[0][g][lane] + red[1][g][lane]
                      + red[2][g][lane] + red[3][g][lane] + hbias;
            float base = fmaf(BETA, mem, xin);
            mem = (mem > THRESH) ? 0.0f : base;
        }
        spk2[b * NH + h] = (mem > THRESH) ? 1.0f : 0.0f;
    }
}

// ---------------- Kernel 3: output layer + softmax ----------------
__global__ __launch_bounds__(256) void k3_out(
    const float* __restrict__ spk2,  // [B][H]
    const float* __restrict__ ow,    // [O][H]
    const float* __restrict__ ob,    // [O]
    float* __restrict__ out)         // [B][O]
{
    int b = blockIdx.x;
    int t = threadIdx.x;

    float p[NO];
    #pragma unroll
    for (int o = 0; o < NO; ++o) p[o] = 0.0f;

    for (int h = t; h < NH; h += 256) {
        float s = spk2[b * NH + h];
        #pragma unroll
        for (int o = 0; o < NO; ++o) p[o] += s * ow[o * NH + h];
    }

    __shared__ float red[NO][256];
    #pragma unroll
    for (int o = 0; o < NO; ++o) red[o][t] = p[o];
    __syncthreads();

    for (int off = 128; off > 0; off >>= 1) {
        if (t < off) {
            #pragma unroll
            for (int o = 0; o < NO; ++o) red[o][t] += red[o][t + off];
        }
        __syncthreads();
    }

    if (t == 0) {
        float v[NO], mx = -1e30f;
        #pragma unroll
        for (int o = 0; o < NO; ++o) { v[o] = red[o][0] + ob[o]; mx = fmaxf(mx, v[o]); }
        float sum = 0.0f;
        #pragma unroll
        for (int o = 0; o < NO; ++o) { v[o] = expf(v[o] - mx); sum += v[o]; }
        float inv = 1.0f / sum;
        #pragma unroll
        for (int o = 0; o < NO; ++o) out[b * NO + o] = v[o] * inv;
    }
}

extern "C" void kernel_launch(void* const* d_in, const int* in_sizes, int n_in,
                              void* d_out, int out_size, void* d_ws, size_t ws_size,
                              hipStream_t stream) {
    const f32x4*  x  = (const f32x4*)d_in[0];   // [32][2000][512][4]
    const float*  cw = (const float*)d_in[1];   // [4]
    const float*  cb = (const float*)d_in[2];   // [1]
    const float*  hw = (const float*)d_in[3];   // [1024][512]
    const float*  hb = (const float*)d_in[4];   // [1024]
    const float*  ow = (const float*)d_in[5];   // [10][1024]
    const float*  ob = (const float*)d_in[6];   // [10]
    float* out = (float*)d_out;                 // [32][10]

    char* ws = (char*)d_ws;
    float* spk1 = (float*)(ws);                           // 32*20*512*4   = 1,310,720 B
    float* wT   = (float*)(ws + 1310720);                 // 512*1024*4    = 2,097,152 B
    float* spk2 = (float*)(ws + 1310720 + 2097152);       // 32*1024*4     =   131,072 B

    // transpose hidden_w (tiny; independent of k1 data)
    k_transpose<<<dim3(16, 32), dim3(32, 8), 0, stream>>>(hw, wT);

    // stage 1: conv + scan1 (~78us, HBM roofline)
    k1_conv_scan<<<(NB * NG * NW) / 256, 256, 0, stream>>>(x, cw, cb, spk1);

    // stage 2+3: hidden GEMM (4-way k-split) + scan2
    // LAUNCHED 5x (idempotent) to measure t(k2)+gap = (dur-134.5)/4.
    k2_hidden_scan<<<NB * 16, 256, 0, stream>>>(spk1, wT, hb, spk2);
    k2_hidden_scan<<<NB * 16, 256, 0, stream>>>(spk1, wT, hb, spk2);
    k2_hidden_scan<<<NB * 16, 256, 0, stream>>>(spk1, wT, hb, spk2);
    k2_hidden_scan<<<NB * 16, 256, 0, stream>>>(spk1, wT, hb, spk2);
    k2_hidden_scan<<<NB * 16, 256, 0, stream>>>(spk1, wT, hb, spk2);

    // stage 4: output + softmax
    k3_out<<<NB, 256, 0, stream>>>(spk2, ow, ob, out);
}

// Round 7
// 120.230 us; speedup vs baseline: 2.4601x; 2.4601x over previous
//
#include <hip/hip_runtime.h>
#include <hip/hip_bf16.h>

typedef float f32x4 __attribute__((ext_vector_type(4)));

#define NB 32      // batch
#define NT 2000    // time
#define NW 512     // width
#define NG 20      // groups (T / NUM_STEPS)
#define NS 100     // NUM_STEPS
#define NH 1024    // hidden
#define NO 10      // outputs
#define BETA 0.95f
#define THRESH 1.0f

// ---------------- Kernel 1: fused 1x1 conv + 100-step leaky scan ----------------
// ROUND-3 VERSION, marginal-measured ~78us (round 5) = HBM roofline. FROZEN.
__global__ __launch_bounds__(256) void k1_conv_scan(
    const f32x4* __restrict__ x,    // [B][T][W] of float4 (C=4 innermost)
    const float* __restrict__ cw,   // [4]
    const float* __restrict__ cb,   // [1]
    float* __restrict__ spk1)       // [B][G][W]
{
    int bid = blockIdx.x;           // 0..1279
    int half = bid & 1;             // which half of the 512-wide row
    int bg = bid >> 1;              // 0..639
    int g = bg % NG;
    int b = bg / NG;
    int tid = threadIdx.x;          // 0..255

    const f32x4* __restrict__ base =
        x + ((size_t)(b * NT + g * NS) * NW + half * 256);

    float w0 = cw[0], w1 = cw[1], w2 = cw[2], w3 = cw[3];
    float bias = cb[0];

    f32x4 A[10], B[10];
    float mem = 0.0f;

#define LOAD10(dst, S0)                                                        \
    {                                                                          \
        _Pragma("unroll")                                                      \
        for (int j = 0; j < 10; ++j)                                           \
            dst[j] = __builtin_nontemporal_load(base + (tid + ((S0) + j) * NW)); \
    }
#define STEP10(src)                                                            \
    {                                                                          \
        _Pragma("unroll")                                                      \
        for (int j = 0; j < 10; ++j) {                                         \
            f32x4 v = src[j];                                                  \
            float f = fmaf(v[0], w0, fmaf(v[1], w1,                            \
                      fmaf(v[2], w2, fmaf(v[3], w3, bias))));                  \
            float base_m = fmaf(BETA, mem, f);                                 \
            mem = (mem > THRESH) ? 0.0f : base_m;                              \
        }                                                                      \
    }

    LOAD10(A, 0)
    LOAD10(B, 10) STEP10(A)
    LOAD10(A, 20) STEP10(B)
    LOAD10(B, 30) STEP10(A)
    LOAD10(A, 40) STEP10(B)
    LOAD10(B, 50) STEP10(A)
    LOAD10(A, 60) STEP10(B)
    LOAD10(B, 70) STEP10(A)
    LOAD10(A, 80) STEP10(B)
    LOAD10(B, 90) STEP10(A)
    STEP10(B)
#undef LOAD10
#undef STEP10

    spk1[(b * NG + g) * NW + half * 256 + tid] = (mem > THRESH) ? 1.0f : 0.0f;
}

// ---------------- Transpose hidden_w (1024x512 -> 512x1024) ----------------
__global__ __launch_bounds__(256) void k_transpose(
    const float* __restrict__ wsrc,  // [H][W]
    float* __restrict__ wT)          // [W][H]
{
    __shared__ float tile[32][33];
    int bk = blockIdx.x;             // 16 tiles over W
    int bh = blockIdx.y;             // 32 tiles over H
    int tx = threadIdx.x;            // 0..31
    int ty = threadIdx.y;            // 0..7
    #pragma unroll
    for (int j = 0; j < 4; ++j)
        tile[ty + j * 8][tx] = wsrc[(bh * 32 + ty + j * 8) * NW + bk * 32 + tx];
    __syncthreads();
    #pragma unroll
    for (int j = 0; j < 4; ++j)
        wT[(bk * 32 + ty + j * 8) * NH + bh * 32 + tx] = tile[tx][ty + j * 8];
}

// ---------------- Kernel 2 v2: hidden GEMM + 20-step scan, LDS-staged spk1 ----
// Round-6 finding: the old "uniform -> s_load" spk1 path serialized on coarse
// lgkmcnt(0) SMEM waits (~1500 cy/iter). v2 stages spk1[b] (40 KB) in LDS and
// reads it as wave-uniform ds_read_b128 BROADCASTS (conflict-free; compiler
// emits fine-grained lgkmcnt for DS), pipelined against coalesced wT loads.
__global__ __launch_bounds__(256) void k2_hidden_scan(
    const float* __restrict__ spk1,  // [B][G][W]
    const float* __restrict__ wT,    // [W][H]
    const float* __restrict__ hb,    // [H]
    float* __restrict__ spk2)        // [B][H]
{
    __shared__ float sk[NG][NW];     // 40 KB: spk1[b] slice
    __shared__ float red[4][NG][64]; // 20 KB: k-chunk partials

    int bid = blockIdx.x;            // 0..511
    int b = bid >> 4;                // 0..31
    int hgrp = bid & 15;             // 0..15
    int t = threadIdx.x;
    int lane = t & 63;
    int c = t >> 6;                  // k-chunk 0..3
    int h = hgrp * 64 + lane;

    // cooperative stage: 2560 float4 / 256 threads = 10 each, coalesced
    {
        const f32x4* __restrict__ sp4 =
            (const f32x4*)(spk1 + (size_t)b * NG * NW);
        f32x4* sk4 = (f32x4*)&sk[0][0];
        #pragma unroll
        for (int i = 0; i < 10; ++i)
            sk4[t + i * 256] = sp4[t + i * 256];
    }
    __syncthreads();

    float acc[NG];
    #pragma unroll
    for (int g = 0; g < NG; ++g) acc[g] = 0.0f;

    int k0 = c * 128;
    #pragma unroll 4
    for (int kk = k0; kk < k0 + 128; kk += 4) {
        float a0 = wT[(kk + 0) * NH + h];
        float a1 = wT[(kk + 1) * NH + h];
        float a2 = wT[(kk + 2) * NH + h];
        float a3 = wT[(kk + 3) * NH + h];
        #pragma unroll
        for (int g = 0; g < NG; ++g) {
            f32x4 u = *(const f32x4*)&sk[g][kk];   // wave-uniform -> broadcast
            acc[g] = fmaf(u[0], a0, fmaf(u[1], a1,
                     fmaf(u[2], a2, fmaf(u[3], a3, acc[g]))));
        }
    }

    #pragma unroll
    for (int g = 0; g < NG; ++g) red[c][g][lane] = acc[g];
    __syncthreads();

    if (t < 64) {
        float hbias = hb[h];
        float mem = 0.0f;
        #pragma unroll
        for (int g = 0; g < NG; ++g) {
            float xin = red[0][g][lane] + red[1][g][lane]
                      + red[2][g][lane] + red[3][g][lane] + hbias;
            float base = fmaf(BETA, mem, xin);
            mem = (mem > THRESH) ? 0.0f : base;
        }
        spk2[b * NH + h] = (mem > THRESH) ? 1.0f : 0.0f;
    }
}

// ---------------- Kernel 3: output layer + softmax ----------------
__global__ __launch_bounds__(256) void k3_out(
    const float* __restrict__ spk2,  // [B][H]
    const float* __restrict__ ow,    // [O][H]
    const float* __restrict__ ob,    // [O]
    float* __restrict__ out)         // [B][O]
{
    int b = blockIdx.x;
    int t = threadIdx.x;

    float p[NO];
    #pragma unroll
    for (int o = 0; o < NO; ++o) p[o] = 0.0f;

    for (int h = t; h < NH; h += 256) {
        float s = spk2[b * NH + h];
        #pragma unroll
        for (int o = 0; o < NO; ++o) p[o] += s * ow[o * NH + h];
    }

    __shared__ float red[NO][256];
    #pragma unroll
    for (int o = 0; o < NO; ++o) red[o][t] = p[o];
    __syncthreads();

    for (int off = 128; off > 0; off >>= 1) {
        if (t < off) {
            #pragma unroll
            for (int o = 0; o < NO; ++o) red[o][t] += red[o][t + off];
        }
        __syncthreads();
    }

    if (t == 0) {
        float v[NO], mx = -1e30f;
        #pragma unroll
        for (int o = 0; o < NO; ++o) { v[o] = red[o][0] + ob[o]; mx = fmaxf(mx, v[o]); }
        float sum = 0.0f;
        #pragma unroll
        for (int o = 0; o < NO; ++o) { v[o] = expf(v[o] - mx); sum += v[o]; }
        float inv = 1.0f / sum;
        #pragma unroll
        for (int o = 0; o < NO; ++o) out[b * NO + o] = v[o] * inv;
    }
}

extern "C" void kernel_launch(void* const* d_in, const int* in_sizes, int n_in,
                              void* d_out, int out_size, void* d_ws, size_t ws_size,
                              hipStream_t stream) {
    const f32x4*  x  = (const f32x4*)d_in[0];   // [32][2000][512][4]
    const float*  cw = (const float*)d_in[1];   // [4]
    const float*  cb = (const float*)d_in[2];   // [1]
    const float*  hw = (const float*)d_in[3];   // [1024][512]
    const float*  hb = (const float*)d_in[4];   // [1024]
    const float*  ow = (const float*)d_in[5];   // [10][1024]
    const float*  ob = (const float*)d_in[6];   // [10]
    float* out = (float*)d_out;                 // [32][10]

    char* ws = (char*)d_ws;
    float* spk1 = (float*)(ws);                           // 32*20*512*4   = 1,310,720 B
    float* wT   = (float*)(ws + 1310720);                 // 512*1024*4    = 2,097,152 B
    float* spk2 = (float*)(ws + 1310720 + 2097152);       // 32*1024*4     =   131,072 B

    // transpose hidden_w (tiny; independent of k1 data)
    k_transpose<<<dim3(16, 32), dim3(32, 8), 0, stream>>>(hw, wT);

    // stage 1: conv + scan1 (~78us, HBM roofline)
    k1_conv_scan<<<(NB * NG * NW) / 256, 256, 0, stream>>>(x, cw, cb, spk1);

    // stage 2+3: hidden GEMM (LDS-staged spk1) + scan2
    k2_hidden_scan<<<NB * 16, 256, 0, stream>>>(spk1, wT, hb, spk2);

    // stage 4: output + softmax
    k3_out<<<NB, 256, 0, stream>>>(spk2, ow, ob, out);
}

// Round 8
// 110.004 us; speedup vs baseline: 2.6888x; 1.0930x over previous
//
#include <hip/hip_runtime.h>
#include <hip/hip_bf16.h>

typedef float f32x4 __attribute__((ext_vector_type(4)));

#define NB 32      // batch
#define NT 2000    // time
#define NW 512     // width
#define NG 20      // groups (T / NUM_STEPS)
#define NS 100     // NUM_STEPS
#define NH 1024    // hidden
#define NO 10      // outputs
#define BETA 0.95f
#define THRESH 1.0f

// ---------------- Kernel 1: fused 1x1 conv + 100-step leaky scan ----------------
// ROUND-3 VERSION, marginal-measured ~78us (round 5) = HBM roofline. FROZEN.
__global__ __launch_bounds__(256) void k1_conv_scan(
    const f32x4* __restrict__ x,    // [B][T][W] of float4 (C=4 innermost)
    const float* __restrict__ cw,   // [4]
    const float* __restrict__ cb,   // [1]
    float* __restrict__ spk1)       // [B][G][W]
{
    int bid = blockIdx.x;           // 0..1279
    int half = bid & 1;             // which half of the 512-wide row
    int bg = bid >> 1;              // 0..639
    int g = bg % NG;
    int b = bg / NG;
    int tid = threadIdx.x;          // 0..255

    const f32x4* __restrict__ base =
        x + ((size_t)(b * NT + g * NS) * NW + half * 256);

    float w0 = cw[0], w1 = cw[1], w2 = cw[2], w3 = cw[3];
    float bias = cb[0];

    f32x4 A[10], B[10];
    float mem = 0.0f;

#define LOAD10(dst, S0)                                                        \
    {                                                                          \
        _Pragma("unroll")                                                      \
        for (int j = 0; j < 10; ++j)                                           \
            dst[j] = __builtin_nontemporal_load(base + (tid + ((S0) + j) * NW)); \
    }
#define STEP10(src)                                                            \
    {                                                                          \
        _Pragma("unroll")                                                      \
        for (int j = 0; j < 10; ++j) {                                         \
            f32x4 v = src[j];                                                  \
            float f = fmaf(v[0], w0, fmaf(v[1], w1,                            \
                      fmaf(v[2], w2, fmaf(v[3], w3, bias))));                  \
            float base_m = fmaf(BETA, mem, f);                                 \
            mem = (mem > THRESH) ? 0.0f : base_m;                              \
        }                                                                      \
    }

    LOAD10(A, 0)
    LOAD10(B, 10) STEP10(A)
    LOAD10(A, 20) STEP10(B)
    LOAD10(B, 30) STEP10(A)
    LOAD10(A, 40) STEP10(B)
    LOAD10(B, 50) STEP10(A)
    LOAD10(A, 60) STEP10(B)
    LOAD10(B, 70) STEP10(A)
    LOAD10(A, 80) STEP10(B)
    LOAD10(B, 90) STEP10(A)
    STEP10(B)
#undef LOAD10
#undef STEP10

    spk1[(b * NG + g) * NW + half * 256 + tid] = (mem > THRESH) ? 1.0f : 0.0f;
}

// ---------------- Transpose hidden_w (1024x512 -> 512x1024) ----------------
__global__ __launch_bounds__(256) void k_transpose(
    const float* __restrict__ wsrc,  // [H][W]
    float* __restrict__ wT)          // [W][H]
{
    __shared__ float tile[32][33];
    int bk = blockIdx.x;             // 16 tiles over W
    int bh = blockIdx.y;             // 32 tiles over H
    int tx = threadIdx.x;            // 0..31
    int ty = threadIdx.y;            // 0..7
    #pragma unroll
    for (int j = 0; j < 4; ++j)
        tile[ty + j * 8][tx] = wsrc[(bh * 32 + ty + j * 8) * NW + bk * 32 + tx];
    __syncthreads();
    #pragma unroll
    for (int j = 0; j < 4; ++j)
        wT[(bk * 32 + ty + j * 8) * NH + bh * 32 + tx] = tile[tx][ty + j * 8];
}

// ---------------- Kernel 2 v3: hidden GEMM + 20-step scan ----------------------
// Round-7 finding: v2's 1:4 ds_read:fma issue ratio + 4 wT loads per 80 FLOP
// left k2 at ~26us (3-4x VALU floor). v3: each thread owns an h-PAIR (float2
// wT loads, lane-consecutive 8B -> coalesced), doubling FMA per broadcast
// ds_read (1:8) and halving VMEM instrs per FLOP. 256 blocks (1/CU) x 256 thr
// = (4 k-chunks x 64 lanes); two-phase LDS reduction keeps static LDS = 60 KB.
__global__ __launch_bounds__(256) void k2_hidden_scan(
    const float* __restrict__ spk1,  // [B][G][W]
    const float* __restrict__ wT,    // [W][H]
    const float* __restrict__ hb,    // [H]
    float* __restrict__ spk2)        // [B][H]
{
    __shared__ float sk[NG][NW];        // 40 KB: spk1[b] slice
    __shared__ float2 red[2][NG][64];   // 20 KB: two-phase partials

    int bid = blockIdx.x;            // 0..255
    int b = bid >> 3;                // 0..31
    int hgrp = bid & 7;              // 0..7 (128 h per block)
    int t = threadIdx.x;
    int lane = t & 63;
    int c = t >> 6;                  // k-chunk 0..3 (128 kk each)
    int h = hgrp * 128 + lane * 2;   // h-pair base

    // cooperative stage: 2560 float4 / 256 threads = 10 each, coalesced
    {
        const f32x4* __restrict__ sp4 =
            (const f32x4*)(spk1 + (size_t)b * NG * NW);
        f32x4* sk4 = (f32x4*)&sk[0][0];
        #pragma unroll
        for (int i = 0; i < 10; ++i)
            sk4[t + i * 256] = sp4[t + i * 256];
    }
    __syncthreads();

    float2 acc[NG];
    #pragma unroll
    for (int g = 0; g < NG; ++g) { acc[g].x = 0.0f; acc[g].y = 0.0f; }

    int k0 = c * 128;
    #pragma unroll 2
    for (int kkg = 0; kkg < 32; ++kkg) {
        int kk = k0 + kkg * 4;
        float2 a0 = *(const float2*)&wT[(kk + 0) * NH + h];
        float2 a1 = *(const float2*)&wT[(kk + 1) * NH + h];
        float2 a2 = *(const float2*)&wT[(kk + 2) * NH + h];
        float2 a3 = *(const float2*)&wT[(kk + 3) * NH + h];
        #pragma unroll
        for (int g = 0; g < NG; ++g) {
            f32x4 u = *(const f32x4*)&sk[g][kk];   // wave-uniform -> broadcast
            acc[g].x = fmaf(u[0], a0.x, fmaf(u[1], a1.x,
                       fmaf(u[2], a2.x, fmaf(u[3], a3.x, acc[g].x))));
            acc[g].y = fmaf(u[0], a0.y, fmaf(u[1], a1.y,
                       fmaf(u[2], a2.y, fmaf(u[3], a3.y, acc[g].y))));
        }
    }

    // two-phase reduction: chunks 0,1 write; chunks 2,3 accumulate in place
    if (c < 2) {
        #pragma unroll
        for (int g = 0; g < NG; ++g) red[c][g][lane] = acc[g];
    }
    __syncthreads();
    if (c >= 2) {
        #pragma unroll
        for (int g = 0; g < NG; ++g) {
            red[c - 2][g][lane].x += acc[g].x;
            red[c - 2][g][lane].y += acc[g].y;
        }
    }
    __syncthreads();

    if (t < 64) {
        float2 hbias = *(const float2*)&hb[hgrp * 128 + t * 2];
        float m0 = 0.0f, m1 = 0.0f;
        #pragma unroll
        for (int g = 0; g < NG; ++g) {
            float x0 = red[0][g][t].x + red[1][g][t].x + hbias.x;
            float x1 = red[0][g][t].y + red[1][g][t].y + hbias.y;
            float b0 = fmaf(BETA, m0, x0);
            float b1 = fmaf(BETA, m1, x1);
            m0 = (m0 > THRESH) ? 0.0f : b0;
            m1 = (m1 > THRESH) ? 0.0f : b1;
        }
        float2 o;
        o.x = (m0 > THRESH) ? 1.0f : 0.0f;
        o.y = (m1 > THRESH) ? 1.0f : 0.0f;
        *(float2*)&spk2[b * NH + hgrp * 128 + t * 2] = o;
    }
}

// ---------------- Kernel 3: output layer + softmax ----------------
__global__ __launch_bounds__(256) void k3_out(
    const float* __restrict__ spk2,  // [B][H]
    const float* __restrict__ ow,    // [O][H]
    const float* __restrict__ ob,    // [O]
    float* __restrict__ out)         // [B][O]
{
    int b = blockIdx.x;
    int t = threadIdx.x;

    float p[NO];
    #pragma unroll
    for (int o = 0; o < NO; ++o) p[o] = 0.0f;

    for (int h = t; h < NH; h += 256) {
        float s = spk2[b * NH + h];
        #pragma unroll
        for (int o = 0; o < NO; ++o) p[o] += s * ow[o * NH + h];
    }

    __shared__ float red[NO][256];
    #pragma unroll
    for (int o = 0; o < NO; ++o) red[o][t] = p[o];
    __syncthreads();

    for (int off = 128; off > 0; off >>= 1) {
        if (t < off) {
            #pragma unroll
            for (int o = 0; o < NO; ++o) red[o][t] += red[o][t + off];
        }
        __syncthreads();
    }

    if (t == 0) {
        float v[NO], mx = -1e30f;
        #pragma unroll
        for (int o = 0; o < NO; ++o) { v[o] = red[o][0] + ob[o]; mx = fmaxf(mx, v[o]); }
        float sum = 0.0f;
        #pragma unroll
        for (int o = 0; o < NO; ++o) { v[o] = expf(v[o] - mx); sum += v[o]; }
        float inv = 1.0f / sum;
        #pragma unroll
        for (int o = 0; o < NO; ++o) out[b * NO + o] = v[o] * inv;
    }
}

extern "C" void kernel_launch(void* const* d_in, const int* in_sizes, int n_in,
                              void* d_out, int out_size, void* d_ws, size_t ws_size,
                              hipStream_t stream) {
    const f32x4*  x  = (const f32x4*)d_in[0];   // [32][2000][512][4]
    const float*  cw = (const float*)d_in[1];   // [4]
    const float*  cb = (const float*)d_in[2];   // [1]
    const float*  hw = (const float*)d_in[3];   // [1024][512]
    const float*  hb = (const float*)d_in[4];   // [1024]
    const float*  ow = (const float*)d_in[5];   // [10][1024]
    const float*  ob = (const float*)d_in[6];   // [10]
    float* out = (float*)d_out;                 // [32][10]

    char* ws = (char*)d_ws;
    float* spk1 = (float*)(ws);                           // 32*20*512*4   = 1,310,720 B
    float* wT   = (float*)(ws + 1310720);                 // 512*1024*4    = 2,097,152 B
    float* spk2 = (float*)(ws + 1310720 + 2097152);       // 32*1024*4     =   131,072 B

    // transpose hidden_w (tiny; independent of k1 data)
    k_transpose<<<dim3(16, 32), dim3(32, 8), 0, stream>>>(hw, wT);

    // stage 1: conv + scan1 (~78us, HBM roofline)
    k1_conv_scan<<<(NB * NG * NW) / 256, 256, 0, stream>>>(x, cw, cb, spk1);

    // stage 2+3: hidden GEMM (h-pair threads, LDS-staged spk1) + scan2
    k2_hidden_scan<<<NB * 8, 256, 0, stream>>>(spk1, wT, hb, spk2);

    // stage 4: output + softmax
    k3_out<<<NB, 256, 0, stream>>>(spk2, ow, ob, out);
}